// Round 1
// baseline (317.081 us; speedup 1.0000x reference)
//
#include <hip/hip_runtime.h>
#include <hip/hip_bf16.h>

#define B_ 16
#define I_ 256
#define O_ 256
#define T_ 512
#define L_ 8192
#define K_ 7
#define PAD_ 3
#define BN 64
#define LDK 264   // X_lds row stride in bf16 elements (256 + 8 pad: keeps b128 reads 16B-aligned & bank-uniform)

typedef unsigned short u16;
typedef unsigned int u32;
typedef __attribute__((ext_vector_type(8))) short short8;
typedef __attribute__((ext_vector_type(4))) float f32x4;

__device__ inline u16 f2bf(float f) {
    union { float f; u32 u; } v; v.f = f;
    u32 r = v.u + 0x7FFF + ((v.u >> 16) & 1);   // RNE
    return (u16)(r >> 16);
}

// ---------------- Kernel 1: mod[b][i] = t[b,:] . mod_w[i,:] + mod_b[i] ----------------
// grid (16 igroup, 16 b), 256 threads; each wave computes 4 i's via lane-parallel dot.
__global__ void mod_kernel(const float* __restrict__ t, const float* __restrict__ mod_w,
                           const float* __restrict__ mod_b, float* __restrict__ mod) {
    int g = blockIdx.x, b = blockIdx.y;
    int lane = threadIdx.x & 63, wv = threadIdx.x >> 6;
    const float* tb = t + b * T_;
    #pragma unroll
    for (int q = 0; q < 4; ++q) {
        int i = g * 16 + wv * 4 + q;
        const float* wr = mod_w + (size_t)i * T_;
        float s = 0.f;
        #pragma unroll
        for (int u = 0; u < 8; ++u) s += wr[lane + u * 64] * tb[lane + u * 64];
        #pragma unroll
        for (int d = 32; d; d >>= 1) s += __shfl_down(s, d);
        if (lane == 0) mod[b * I_ + i] = s + mod_b[i];
    }
}

// ---------------- Kernel 2: Wb[b][o][i] = bf16( proj_w[o,i]*(mod[b,i]+1) * demod[b,o] ) ----
// grid (16 ogroup, 16 b), 256 threads; each wave handles 4 o's; butterfly reduce for sum(bw^2).
__global__ void wmod_kernel(const float* __restrict__ proj_w, const float* __restrict__ mod,
                            u16* __restrict__ Wb) {
    int og = blockIdx.x, b = blockIdx.y;
    int lane = threadIdx.x & 63, wv = threadIdx.x >> 6;
    const float* mrow = mod + b * I_;
    #pragma unroll
    for (int q = 0; q < 4; ++q) {
        int o = og * 16 + wv * 4 + q;
        const float* pw = proj_w + (size_t)o * I_;
        float4 pv = *(const float4*)(pw + lane * 4);
        float4 mv = *(const float4*)(mrow + lane * 4);
        float v0 = pv.x * (mv.x + 1.f);
        float v1 = pv.y * (mv.y + 1.f);
        float v2 = pv.z * (mv.z + 1.f);
        float v3 = pv.w * (mv.w + 1.f);
        float ss = v0*v0 + v1*v1 + v2*v2 + v3*v3;
        #pragma unroll
        for (int d = 32; d; d >>= 1) ss += __shfl_xor(ss, d);
        float dem = rsqrtf(ss + 1e-8f);
        u32 lo = (u32)f2bf(v0 * dem) | ((u32)f2bf(v1 * dem) << 16);
        u32 hi = (u32)f2bf(v2 * dem) | ((u32)f2bf(v3 * dem) << 16);
        *(uint2*)(Wb + (size_t)(b * O_ + o) * I_ + lane * 4) = make_uint2(lo, hi);
    }
}

// ---------------- Kernel 3: fused depthwise-conv + batched GEMM ----------------
// grid (128 l-tiles, 16 b), 256 threads = 4 waves.
// Phase 1: X_lds[n][i] = bf16(conv(bx)) for n in [0,64), i in [0,256)  (k-contiguous = B-frag layout)
// Phase 2: C(256x64) = W(256x256) * X(256x64), 16x16x32 bf16 MFMA, A-frags direct from L2.
__global__ __launch_bounds__(256) void main_kernel(
    const float* __restrict__ bx, const float* __restrict__ conv_w,
    const u16* __restrict__ Wb, const float* __restrict__ proj_b,
    float* __restrict__ out)
{
    __shared__ __align__(16) u16 Xs[BN * LDK];   // 33,792 B

    const int tile = blockIdx.x;
    const int b = blockIdx.y;
    const int l0 = tile * BN;
    const int tid = threadIdx.x;
    const int lane = tid & 63;
    const int wv = tid >> 6;
    const int mlane = lane & 15;
    const int quad = lane >> 4;

    // ---- Phase 1: depthwise conv ----
    // thread owns 4 fixed channels i0..i0+3 (weights cached in regs), sweeps l in 4 iters of 16.
    const int rq = tid >> 2;        // 0..63  -> i0 = 4*rq
    const int lq = tid & 3;         // 0..3   -> l offset within iter
    const int i0 = rq * 4;
    const float* bxr = bx + (size_t)b * I_ * L_;
    const bool interior = (l0 >= 4) && (l0 + 72 <= L_);

    float wr[4][K_];
    #pragma unroll
    for (int di = 0; di < 4; ++di)
        #pragma unroll
        for (int j = 0; j < K_; ++j)
            wr[di][j] = conv_w[(i0 + di) * K_ + j];

    for (int it = 0; it < 4; ++it) {
        const int lb = it * 16 + lq * 4;   // 0..60
        u16 hv[4][4];                      // [dl][di]
        #pragma unroll
        for (int di = 0; di < 4; ++di) {
            const float* row = bxr + (size_t)(i0 + di) * L_ + l0;
            float x[12];                   // window [lb-4, lb+12)
            if (interior) {
                const float4* rp = (const float4*)(row + lb - 4);
                float4 w0 = rp[0], w1 = rp[1], w2 = rp[2];
                x[0]=w0.x; x[1]=w0.y; x[2]=w0.z; x[3]=w0.w;
                x[4]=w1.x; x[5]=w1.y; x[6]=w1.z; x[7]=w1.w;
                x[8]=w2.x; x[9]=w2.y; x[10]=w2.z; x[11]=w2.w;
            } else {
                #pragma unroll
                for (int w = 0; w < 12; ++w) {
                    int p = l0 + lb - 4 + w;
                    x[w] = (p >= 0 && p < L_) ? row[lb - 4 + w] : 0.f;
                }
            }
            #pragma unroll
            for (int dl = 0; dl < 4; ++dl) {
                float a = 0.f;
                #pragma unroll
                for (int j = 0; j < K_; ++j) a += wr[di][j] * x[dl + 1 + j];
                hv[dl][di] = f2bf(a);
            }
        }
        #pragma unroll
        for (int dl = 0; dl < 4; ++dl) {
            int n = lb + dl;
            u32 lo = (u32)hv[dl][0] | ((u32)hv[dl][1] << 16);
            u32 hi = (u32)hv[dl][2] | ((u32)hv[dl][3] << 16);
            *(uint2*)(&Xs[n * LDK + i0]) = make_uint2(lo, hi);
        }
    }
    __syncthreads();

    // ---- Phase 2: GEMM ----
    // wave wv owns output rows m in [64*wv, 64*wv+64): 4 m-frags x 4 n-frags of 16x16.
    f32x4 acc[4][4];
    #pragma unroll
    for (int r = 0; r < 4; ++r)
        #pragma unroll
        for (int c = 0; c < 4; ++c)
            acc[r][c] = (f32x4){0.f, 0.f, 0.f, 0.f};

    const u16* Wrow = Wb + (size_t)(b * O_ + wv * 64 + mlane) * I_;

    for (int kb = 0; kb < 8; ++kb) {
        const int koff = kb * 32 + quad * 8;
        short8 a[4], bbf[4];
        #pragma unroll
        for (int r = 0; r < 4; ++r)
            a[r] = *(const short8*)(Wrow + r * 16 * I_ + koff);
        #pragma unroll
        for (int c = 0; c < 4; ++c)
            bbf[c] = *(const short8*)(&Xs[(c * 16 + mlane) * LDK + koff]);
        #pragma unroll
        for (int r = 0; r < 4; ++r)
            #pragma unroll
            for (int c = 0; c < 4; ++c)
                acc[r][c] = __builtin_amdgcn_mfma_f32_16x16x32_bf16(a[r], bbf[c], acc[r][c], 0, 0, 0);
    }

    // ---- Epilogue: + proj_b, store ----
    float* outb = out + (size_t)b * O_ * L_;
    #pragma unroll
    for (int r = 0; r < 4; ++r) {
        const int obase = wv * 64 + r * 16 + quad * 4;
        #pragma unroll
        for (int p = 0; p < 4; ++p) {
            const int o = obase + p;
            const float bias = proj_b[o];
            float* orow = outb + (size_t)o * L_ + l0 + mlane;
            #pragma unroll
            for (int c = 0; c < 4; ++c)
                orow[c * 16] = acc[r][c][p] + bias;
        }
    }
}

extern "C" void kernel_launch(void* const* d_in, const int* in_sizes, int n_in,
                              void* d_out, int out_size, void* d_ws, size_t ws_size,
                              hipStream_t stream) {
    const float* bx     = (const float*)d_in[0];
    const float* t      = (const float*)d_in[1];
    const float* conv_w = (const float*)d_in[2];
    const float* proj_w = (const float*)d_in[3];
    const float* proj_b = (const float*)d_in[4];
    const float* mod_w  = (const float*)d_in[5];
    const float* mod_b  = (const float*)d_in[6];
    float* out = (float*)d_out;

    float* mod = (float*)d_ws;                       // 16 KB
    u16*   Wb  = (u16*)((char*)d_ws + 16384);        // 256 KB bf16 modulated weights

    mod_kernel<<<dim3(16, 16), 256, 0, stream>>>(t, mod_w, mod_b, mod);
    wmod_kernel<<<dim3(16, 16), 256, 0, stream>>>(proj_w, mod, Wb);
    main_kernel<<<dim3(128, 16), 256, 0, stream>>>(bx, conv_w, Wb, proj_b, out);
}